// Round 7
// baseline (1361.248 us; speedup 1.0000x reference)
//
#include <hip/hip_runtime.h>
#include <hip/hip_bf16.h>

// ---- VQ-VAE forward, round 7 ----------------------------------------------
// r6 diagnosis: dc2 FETCH 332MB vs 64MB input -- A-reads replicated 8x
// (4 parity cls x 2 co-groups as separate blocks), blown L2. r7: one block
// covers all 128 co (NT=4, S=2) AND loops the 4 parity classes internally
// (per-cls epilogue + acc reset); B slices stream [cls][tap] through the
// LDS double-buffer. A footprint /8 for dc1/dc2, /2 for conv2. conv4 S=8.
// Layouts (HW-verified): 32x32x16_bf16 A[m=lane&31][k=(lane>>5)*8+j],
//   D: col=lane&31, row=(reg&3)+8*(reg>>2)+4*(lane>>5).
// 16x16x32_bf16 A[m=lane&15][k=(lane>>4)*8+j], D: col=lane&15,
//   row=(lane>>4)*4+reg.
// Deconv k4s2p1 parity (a,b): out(2q+a,2r+b) += in(q+a-i, r+b-j)*
//   w[ci][co][2i+1-a][2j+1-b]  (verified r2-r6).

typedef __attribute__((ext_vector_type(8))) short short8;
typedef __attribute__((ext_vector_type(16))) float f32x16;
typedef __attribute__((ext_vector_type(4))) float f32x4;

__device__ __forceinline__ unsigned short f2bf(float f) {
  union { __hip_bfloat16 b; unsigned short u; } cv;
  cv.b = __float2bfloat16(f);
  return cv.u;
}
__device__ __forceinline__ unsigned pack2bf(float a, float b) {
  return (unsigned)f2bf(a) | ((unsigned)f2bf(b) << 16);
}

// ---------------- weight repack: conv layers  w[CO][CI][NTAP] fp32 -> frags
// layout: [tap][kc][ntall][lane][8]
template<int CI, int NTAP, int NTALL>
__global__ void repack_conv_w(const float* __restrict__ w,
                              unsigned short* __restrict__ wb, int co_real) {
  const int KC = CI / 16;
  const int total = NTAP * KC * NTALL * 512;
  int i = blockIdx.x * 256 + threadIdx.x;
  if (i >= total) return;
  int j = i & 7, lane = (i >> 3) & 63, t2 = i >> 9;
  int nt = t2 % NTALL; t2 /= NTALL;
  int kc = t2 % KC; int tap = t2 / KC;
  int co = nt * 32 + (lane & 31);
  int ci = kc * 16 + (lane >> 5) * 8 + j;
  float v = (co < co_real) ? w[(co * CI + ci) * NTAP + tap] : 0.f;
  wb[i] = f2bf(v);
}

// ---------------- weight repack: deconv  w[CI][CO][4][4] fp32 -> frags/class
// layout: [cls][tap][kc][ntall][lane][8]
template<int CI, int CO, int NTALL>
__global__ void repack_deconv_w(const float* __restrict__ w,
                                unsigned short* __restrict__ wb) {
  const int KC = CI / 16;
  const int total = 16 * KC * NTALL * 512;
  int i = blockIdx.x * 256 + threadIdx.x;
  if (i >= total) return;
  int j = i & 7, lane = (i >> 3) & 63, t2 = i >> 9;
  int nt = t2 % NTALL; t2 /= NTALL;
  int kc = t2 % KC; t2 /= KC;
  int tap = t2 & 3, cls = t2 >> 2;
  int a = cls >> 1, b = cls & 1, ti = tap >> 1, tj = tap & 1;
  int kh = 2 * ti + 1 - a, kw = 2 * tj + 1 - b;
  int co = nt * 32 + (lane & 31);
  int ci = kc * 16 + (lane >> 5) * 8 + j;
  wb[i] = f2bf(w[((ci * CO + co) * 4 + kh) * 4 + kw]);
}

// ---------------- weight repack: conv4 16x16 frags  dw3[3][128][3][3]
__global__ void repack_conv4_w(const float* __restrict__ w,
                               unsigned short* __restrict__ wb) {
  const int total = 9 * 4 * 512;
  int i = blockIdx.x * 256 + threadIdx.x;
  if (i >= total) return;
  int j = i & 7, lane = (i >> 3) & 63, tk = i >> 9;
  int kc = tk & 3, t = tk >> 2;
  int co = lane & 15;
  int ci = kc * 32 + (lane >> 4) * 8 + j;
  float v = (co < 3) ? w[(co * 128 + ci) * 9 + t] : 0.f;
  wb[i] = f2bf(v);
}

// ---------------- weight repack: conv1  ew1[128][3][4][4] -> wc1[tap*128+co] fp32
__global__ void repack_conv1_w(const float* __restrict__ w,
                               float* __restrict__ wc1) {
  int i = blockIdx.x * 256 + threadIdx.x;   // 6144
  if (i >= 6144) return;
  int tap = i >> 7, co = i & 127;
  wc1[i] = w[co * 48 + tap];
}

// ---------------- codebook repack -> bf16 B-frags [tile16][kc4][lane64][8]
__global__ void repack_cb(const float* __restrict__ cb,
                          unsigned short* __restrict__ cbf) {
  int i = blockIdx.x * 256 + threadIdx.x;   // 32768
  int j = i & 7, lane = (i >> 3) & 63;
  int kc = (i >> 9) & 3, tile = i >> 11;
  int code = tile * 32 + (lane & 31);
  int d = kc * 16 + (lane >> 5) * 8 + j;
  cbf[i] = f2bf(cb[code * 64 + d]);
}
__global__ void cnorm_k(const float* __restrict__ cb, float* __restrict__ cn) {
  int k = blockIdx.x * 256 + threadIdx.x;
  if (k >= 512) return;
  const float4* r = (const float4*)(cb + k * 64);
  float s = 0.f;
  #pragma unroll
  for (int q = 0; q < 16; ++q) {
    float4 v = r[q];
    s = fmaf(v.x, v.x, s); s = fmaf(v.y, v.y, s);
    s = fmaf(v.z, v.z, s); s = fmaf(v.w, v.w, s);
  }
  cn[k] = s;
}

// ---------------- conv1 v2: x NCHW fp32 [64,3,128,128] -> h1 NHWC bf16
__global__ __launch_bounds__(256, 4) void conv1_k(
    const float* __restrict__ x, const float* __restrict__ wc1,
    const float* __restrict__ bias, unsigned short* __restrict__ out) {
  __shared__ float swc[6144];          // [tap][co] 24 KB
  __shared__ float sx[3 * 10 * 132];   // [ci][r][c] 15.8 KB
  int tid = threadIdx.x;
  int n = blockIdx.x >> 4, ohq = blockIdx.x & 15;
  #pragma unroll
  for (int q = 0; q < 6; ++q) {
    int i = (q * 256 + tid) * 4;
    *(float4*)&swc[i] = *(const float4*)&wc1[i];
  }
  int ihb = 8 * ohq - 1;
  for (int i = tid; i < 3960; i += 256) {
    int ci = i / 1320, rem = i - ci * 1320;
    int r = rem / 132, c = rem - r * 132;
    int ih = ihb + r, iw = c - 1;
    float v = 0.f;
    if ((unsigned)ih < 128u && (unsigned)iw < 128u)
      v = x[(n * 3 + ci) * 16384 + ih * 128 + iw];
    sx[i] = v;
  }
  __syncthreads();
  int ow = tid >> 2, cg = tid & 3;
  #pragma unroll
  for (int cob = 0; cob < 2; ++cob) {
    int co0 = cob * 64 + cg * 16;
    float4 acc[4][4];
    float4 bq[4];
    #pragma unroll
    for (int q = 0; q < 4; ++q) bq[q] = *(const float4*)&bias[co0 + q * 4];
    #pragma unroll
    for (int o = 0; o < 4; ++o)
      #pragma unroll
      for (int q = 0; q < 4; ++q) acc[o][q] = bq[q];
    for (int ci = 0; ci < 3; ++ci)
      for (int kh = 0; kh < 4; ++kh) {
        #pragma unroll
        for (int kw = 0; kw < 4; ++kw) {
          int tap = ci * 16 + kh * 4 + kw;
          const float* wp = &swc[tap * 128 + co0];
          float4 w0 = *(const float4*)(wp);
          float4 w1 = *(const float4*)(wp + 4);
          float4 w2 = *(const float4*)(wp + 8);
          float4 w3 = *(const float4*)(wp + 12);
          const float* xp = &sx[ci * 1320 + kh * 132 + 2 * ow + kw];
          #pragma unroll
          for (int o = 0; o < 4; ++o) {
            float xv = xp[o * 264];
            acc[o][0].x = fmaf(xv, w0.x, acc[o][0].x);
            acc[o][0].y = fmaf(xv, w0.y, acc[o][0].y);
            acc[o][0].z = fmaf(xv, w0.z, acc[o][0].z);
            acc[o][0].w = fmaf(xv, w0.w, acc[o][0].w);
            acc[o][1].x = fmaf(xv, w1.x, acc[o][1].x);
            acc[o][1].y = fmaf(xv, w1.y, acc[o][1].y);
            acc[o][1].z = fmaf(xv, w1.z, acc[o][1].z);
            acc[o][1].w = fmaf(xv, w1.w, acc[o][1].w);
            acc[o][2].x = fmaf(xv, w2.x, acc[o][2].x);
            acc[o][2].y = fmaf(xv, w2.y, acc[o][2].y);
            acc[o][2].z = fmaf(xv, w2.z, acc[o][2].z);
            acc[o][2].w = fmaf(xv, w2.w, acc[o][2].w);
            acc[o][3].x = fmaf(xv, w3.x, acc[o][3].x);
            acc[o][3].y = fmaf(xv, w3.y, acc[o][3].y);
            acc[o][3].z = fmaf(xv, w3.z, acc[o][3].z);
            acc[o][3].w = fmaf(xv, w3.w, acc[o][3].w);
          }
        }
      }
    #pragma unroll
    for (int o = 0; o < 4; ++o) {
      int oh = ohq * 4 + o;
      unsigned short* op = out + ((size_t)(n * 64 + oh) * 64 + ow) * 128 + co0;
      uint4 u0, u1;
      u0.x = pack2bf(fmaxf(acc[o][0].x, 0.f), fmaxf(acc[o][0].y, 0.f));
      u0.y = pack2bf(fmaxf(acc[o][0].z, 0.f), fmaxf(acc[o][0].w, 0.f));
      u0.z = pack2bf(fmaxf(acc[o][1].x, 0.f), fmaxf(acc[o][1].y, 0.f));
      u0.w = pack2bf(fmaxf(acc[o][1].z, 0.f), fmaxf(acc[o][1].w, 0.f));
      u1.x = pack2bf(fmaxf(acc[o][2].x, 0.f), fmaxf(acc[o][2].y, 0.f));
      u1.y = pack2bf(fmaxf(acc[o][2].z, 0.f), fmaxf(acc[o][2].w, 0.f));
      u1.z = pack2bf(fmaxf(acc[o][3].x, 0.f), fmaxf(acc[o][3].y, 0.f));
      u1.w = pack2bf(fmaxf(acc[o][3].z, 0.f), fmaxf(acc[o][3].w, 0.f));
      *(uint4*)(op) = u0;
      *(uint4*)(op + 8) = u1;
    }
  }
}

// ---------------- generic MFMA conv / parity-deconv (r7)
// Block: 4 waves, M = 4*S*32, N = 32*NT = CO (no co-groups).
// Deconv: NCLS=4 parity classes looped internally; per-cls epilogue.
// B slices stream [cls][tap][kc][nt] through LDS double-buffer.
template<int CI, int CO, int NT, int S, int IH, int IW, int OH, int OW,
         int NTAP, int KW, int STRIDE, int NCLS, bool RELU, bool F32OUT>
__global__ __launch_bounds__(256, 2) void mconv_k(
    const unsigned short* __restrict__ in, const unsigned short* __restrict__ wb,
    const float* __restrict__ bias, void* __restrict__ outv,
    const unsigned short* __restrict__ zeropg) {
  const int KC = CI / 16;
  const int TSZ = KC * NT * 512;       // shorts per staged tap slice
  const int STG = KC * NT / 4;         // uint4 per thread per stage
  const int TT = NCLS * NTAP;
  const bool DECONV = (NCLS > 1);
  __shared__ unsigned short sB[2][TSZ];
  int tid = threadIdx.x, lane = tid & 63, wv = tid >> 6;
  int m0 = blockIdx.x * (4 * S * 32) + wv * (32 * S);
  int khalf = lane >> 5;
  int n_[S], oh_[S], ow_[S];
  #pragma unroll
  for (int s = 0; s < S; ++s) {
    int mm = m0 + s * 32 + (lane & 31);
    n_[s] = mm / (OH * OW);
    int rem = mm % (OH * OW);
    oh_[s] = rem / OW; ow_[s] = rem % OW;
  }
  f32x16 acc[S][NT];
  #pragma unroll
  for (int s = 0; s < S; ++s)
    #pragma unroll
    for (int t = 0; t < NT; ++t)
      #pragma unroll
      for (int e = 0; e < 16; ++e) acc[s][t][e] = 0.f;

  uint4 st[STG];
  // prologue: stage slice 0 into buf 0
  #pragma unroll
  for (int q = 0; q < STG; ++q)
    st[q] = *(const uint4*)(wb + (q * 256 + tid) * 8);
  #pragma unroll
  for (int q = 0; q < STG; ++q)
    *(uint4*)&sB[0][(q * 256 + tid) * 8] = st[q];
  __syncthreads();

  int col = lane & 31;
  for (int tt = 0; tt < TT; ++tt) {
    int cur = tt & 1;
    int cls = DECONV ? (tt / NTAP) : 0;
    int tap = DECONV ? (tt % NTAP) : tt;
    int ca = cls >> 1, cb2 = cls & 1;
    if (tt + 1 < TT) {
      const unsigned short* wt = wb + (size_t)(tt + 1) * TSZ;
      #pragma unroll
      for (int q = 0; q < STG; ++q)
        st[q] = *(const uint4*)(wt + (q * 256 + tid) * 8);
    }
    const unsigned short* ap[S];
    #pragma unroll
    for (int s = 0; s < S; ++s) {
      int ih, iw;
      if (DECONV) { ih = oh_[s] + ca - (tap >> 1); iw = ow_[s] + cb2 - (tap & 1); }
      else        { ih = STRIDE * oh_[s] - 1 + tap / KW; iw = STRIDE * ow_[s] - 1 + tap % KW; }
      bool valid = ((unsigned)ih < (unsigned)IH) && ((unsigned)iw < (unsigned)IW);
      ap[s] = valid ? (in + ((size_t)(n_[s] * IH + ih) * IW + iw) * CI + khalf * 8)
                    : (zeropg + khalf * 8);
    }
    #pragma unroll
    for (int kc = 0; kc < KC; ++kc) {
      short8 a[S];
      #pragma unroll
      for (int s = 0; s < S; ++s) a[s] = *(const short8*)(ap[s] + kc * 16);
      #pragma unroll
      for (int nt = 0; nt < NT; ++nt) {
        short8 b = *(const short8*)&sB[cur][(kc * NT + nt) * 512 + lane * 8];
        #pragma unroll
        for (int s = 0; s < S; ++s)
          acc[s][nt] = __builtin_amdgcn_mfma_f32_32x32x16_bf16(a[s], b, acc[s][nt], 0, 0, 0);
      }
    }
    if (tt + 1 < TT) {
      #pragma unroll
      for (int q = 0; q < STG; ++q)
        *(uint4*)&sB[cur ^ 1][(q * 256 + tid) * 8] = st[q];
    }
    // per-class epilogue (deconv): write + reset acc
    if (DECONV && tap == NTAP - 1) {
      #pragma unroll
      for (int s = 0; s < S; ++s)
        #pragma unroll
        for (int nt = 0; nt < NT; ++nt) {
          int co = nt * 32 + col;
          float bv = bias[co];
          #pragma unroll
          for (int r = 0; r < 16; ++r) {
            int mrow = (r & 3) + 8 * (r >> 2) + 4 * khalf;
            int mp = m0 + s * 32 + mrow;
            int n2 = mp / (OH * OW), r2 = mp % (OH * OW);
            int oh2 = r2 / OW, ow2 = r2 % OW;
            float v = acc[s][nt][r] + bv;
            if (RELU) v = fmaxf(v, 0.f);
            size_t idx = ((size_t)(n2 * (2 * OH) + 2 * oh2 + ca) * (2 * OW) + 2 * ow2 + cb2) * CO + co;
            if (F32OUT) ((float*)outv)[idx] = v;
            else        ((unsigned short*)outv)[idx] = f2bf(v);
            acc[s][nt][r] = 0.f;
          }
        }
    }
    __syncthreads();
  }

  if (!DECONV) {
    #pragma unroll
    for (int s = 0; s < S; ++s)
      #pragma unroll
      for (int nt = 0; nt < NT; ++nt) {
        int co = nt * 32 + col;
        float bv = bias[co];
        #pragma unroll
        for (int r = 0; r < 16; ++r) {
          int mrow = (r & 3) + 8 * (r >> 2) + 4 * khalf;
          int mp = m0 + s * 32 + mrow;
          int n2 = mp / (OH * OW), r2 = mp % (OH * OW);
          int oh2 = r2 / OW, ow2 = r2 % OW;
          float v = acc[s][nt][r] + bv;
          if (RELU) v = fmaxf(v, 0.f);
          size_t idx = ((size_t)(n2 * OH + oh2) * OW + ow2) * CO + co;
          if (F32OUT) ((float*)outv)[idx] = v;
          else        ((unsigned short*)outv)[idx] = f2bf(v);
        }
      }
  }
}

// ---------------- VQ via MFMA, codebook frags staged in LDS (2 phases x 32KB)
__global__ __launch_bounds__(256, 2) void vq2_k(
    const float* __restrict__ ze, const float* __restrict__ cb,
    const unsigned short* __restrict__ cbf, const float* __restrict__ cnorm,
    unsigned short* __restrict__ zq, float* __restrict__ acc_loss) {
  __shared__ unsigned short sC[16384];   // 8 tiles of B-frags (32 KB)
  __shared__ int s_idx[4][32];
  int tid = threadIdx.x, lane = tid & 63, wv = tid >> 6;
  int m0 = blockIdx.x * 128 + wv * 32;
  int col = lane & 31, khalf = lane >> 5;
  const float* zrow = ze + (size_t)(m0 + col) * 64 + khalf * 8;
  short8 af[4];
  #pragma unroll
  for (int kc = 0; kc < 4; ++kc) {
    float4 a = *(const float4*)(zrow + kc * 16);
    float4 b = *(const float4*)(zrow + kc * 16 + 4);
    short8 f;
    f[0] = (short)f2bf(a.x); f[1] = (short)f2bf(a.y);
    f[2] = (short)f2bf(a.z); f[3] = (short)f2bf(a.w);
    f[4] = (short)f2bf(b.x); f[5] = (short)f2bf(b.y);
    f[6] = (short)f2bf(b.z); f[7] = (short)f2bf(b.w);
    af[kc] = f;
  }
  float best[16]; int bidx[16];
  #pragma unroll
  for (int r = 0; r < 16; ++r) { best[r] = 3.4e38f; bidx[r] = 0; }
  for (int half = 0; half < 2; ++half) {
    #pragma unroll
    for (int q = 0; q < 8; ++q) {
      int i = q * 256 + tid;
      *(uint4*)&sC[i * 8] = *(const uint4*)(cbf + half * 16384 + i * 8);
    }
    __syncthreads();
    #pragma unroll
    for (int t8 = 0; t8 < 8; ++t8) {
      int tt = half * 8 + t8;
      f32x16 acc;
      #pragma unroll
      for (int e = 0; e < 16; ++e) acc[e] = 0.f;
      #pragma unroll
      for (int kc = 0; kc < 4; ++kc) {
        short8 bf_ = *(const short8*)&sC[(t8 * 4 + kc) * 512 + lane * 8];
        acc = __builtin_amdgcn_mfma_f32_32x32x16_bf16(af[kc], bf_, acc, 0, 0, 0);
      }
      float cn = cnorm[tt * 32 + col];
      int code = tt * 32 + col;
      #pragma unroll
      for (int r = 0; r < 16; ++r) {
        float d = fmaf(-2.f, acc[r], cn);
        if (d < best[r]) { best[r] = d; bidx[r] = code; }
      }
    }
    __syncthreads();
  }
  #pragma unroll
  for (int off = 1; off < 32; off <<= 1) {
    #pragma unroll
    for (int r = 0; r < 16; ++r) {
      float ob = __shfl_xor(best[r], off, 64);
      int   oi = __shfl_xor(bidx[r], off, 64);
      if (ob < best[r]) { best[r] = ob; bidx[r] = oi; }
    }
  }
  if (col == 0) {
    #pragma unroll
    for (int r = 0; r < 16; ++r)
      s_idx[wv][(r & 3) + 8 * (r >> 2) + 4 * khalf] = bidx[r];
  }
  __syncthreads();
  int row = lane >> 1, half2 = lane & 1;
  int m = m0 + row;
  int idx = s_idx[wv][row];
  const float4* crow = (const float4*)(cb + idx * 64 + half2 * 32);
  const float4* zp = (const float4*)(ze + (size_t)m * 64 + half2 * 32);
  uint2* zqp = (uint2*)(zq + (size_t)m * 64 + half2 * 32);
  float lsum = 0.f;
  #pragma unroll
  for (int q = 0; q < 8; ++q) {
    float4 c4 = crow[q];
    float4 z4 = zp[q];
    uint2 u; u.x = pack2bf(c4.x, c4.y); u.y = pack2bf(c4.z, c4.w);
    zqp[q] = u;
    float d;
    d = z4.x - c4.x; lsum = fmaf(d, d, lsum);
    d = z4.y - c4.y; lsum = fmaf(d, d, lsum);
    d = z4.z - c4.z; lsum = fmaf(d, d, lsum);
    d = z4.w - c4.w; lsum = fmaf(d, d, lsum);
  }
  #pragma unroll
  for (int off = 32; off > 0; off >>= 1) lsum += __shfl_down(lsum, off, 64);
  if (lane == 0) atomicAdd(acc_loss, lsum);
}

// ---------------- conv4: d2 NHWC bf16 -> x_recon NCHW fp32 (+recon loss)
// 16x16x32 MFMA, N=16 (co pad 3->16), M=128/wave (8 subtiles); B in LDS.
__global__ __launch_bounds__(256, 2) void conv4_k(
    const unsigned short* __restrict__ in, const unsigned short* __restrict__ wb,
    const float* __restrict__ bias, const float* __restrict__ x,
    float* __restrict__ out, float* __restrict__ acc_loss,
    const unsigned short* __restrict__ zeropg) {
  __shared__ unsigned short sW[18432];   // 9 taps x 4 kc x 512 (36 KB)
  int tid = threadIdx.x, lane = tid & 63, wv = tid >> 6;
  #pragma unroll
  for (int q = 0; q < 9; ++q) {
    int i = q * 256 + tid;
    *(uint4*)&sW[i * 8] = *(const uint4*)(wb + i * 8);
  }
  int m0 = blockIdx.x * 512 + wv * 128;
  int quad = lane >> 4, mloc = lane & 15;
  int n_[8], oh_[8], ow_[8];
  #pragma unroll
  for (int s = 0; s < 8; ++s) {
    int mm = m0 + s * 16 + mloc;
    n_[s] = mm >> 14;
    int rem = mm & 16383;
    oh_[s] = rem >> 7; ow_[s] = rem & 127;
  }
  f32x4 acc[8];
  #pragma unroll
  for (int s = 0; s < 8; ++s)
    #pragma unroll
    for (int e = 0; e < 4; ++e) acc[s][e] = 0.f;
  __syncthreads();
  #pragma unroll
  for (int t = 0; t < 9; ++t) {
    int dh = t / 3 - 1, dw = t % 3 - 1;
    const unsigned short* ap[8];
    #pragma unroll
    for (int s = 0; s < 8; ++s) {
      int ih = oh_[s] + dh, iw = ow_[s] + dw;
      bool valid = ((unsigned)ih < 128u) && ((unsigned)iw < 128u);
      ap[s] = valid ? (in + ((size_t)(n_[s] * 128 + ih) * 128 + iw) * 128 + quad * 8)
                    : (zeropg + quad * 8);
    }
    #pragma unroll
    for (int kc = 0; kc < 4; ++kc) {
      short8 bf_ = *(const short8*)&sW[(t * 4 + kc) * 512 + lane * 8];
      #pragma unroll
      for (int s = 0; s < 8; ++s) {
        short8 a = *(const short8*)(ap[s] + kc * 32);
        acc[s] = __builtin_amdgcn_mfma_f32_16x16x32_bf16(a, bf_, acc[s], 0, 0, 0);
      }
    }
  }
  int co = lane & 15;
  float bv = (co < 3) ? bias[co] : 0.f;
  float lsum = 0.f;
  #pragma unroll
  for (int s = 0; s < 8; ++s)
    #pragma unroll
    for (int r = 0; r < 4; ++r) {
      int m = m0 + s * 16 + quad * 4 + r;
      if (co < 3) {
        float v = acc[s][r] + bv;
        int n2 = m >> 14, r2 = m & 16383;
        int gi = (n2 * 3 + co) * 16384 + r2;
        out[gi] = v;
        float d = v - x[gi];
        lsum = fmaf(d, d, lsum);
      }
    }
  #pragma unroll
  for (int off = 32; off > 0; off >>= 1) lsum += __shfl_down(lsum, off, 64);
  if (lane == 0) atomicAdd(acc_loss, lsum);
}

// ---------------- finalize losses
__global__ void finalize_k(const float* __restrict__ accv, float* __restrict__ out) {
  if (threadIdx.x == 0 && blockIdx.x == 0) {
    float recon = accv[0] / 3145728.0f;
    float vq = 1.25f * accv[1] / 4194304.0f;
    out[3145728] = recon + vq;
    out[3145729] = recon;
    out[3145730] = vq;
  }
}

extern "C" void kernel_launch(void* const* d_in, const int* in_sizes, int n_in,
                              void* d_out, int out_size, void* d_ws, size_t ws_size,
                              hipStream_t stream) {
  const float* x   = (const float*)d_in[0];
  const float* ew1 = (const float*)d_in[1];
  const float* eb1 = (const float*)d_in[2];
  const float* ew2 = (const float*)d_in[3];
  const float* eb2 = (const float*)d_in[4];
  const float* ew3 = (const float*)d_in[5];
  const float* eb3 = (const float*)d_in[6];
  const float* cb  = (const float*)d_in[7];
  const float* dw1 = (const float*)d_in[8];
  const float* db1 = (const float*)d_in[9];
  const float* dw2 = (const float*)d_in[10];
  const float* db2 = (const float*)d_in[11];
  const float* dw3 = (const float*)d_in[12];
  const float* db3 = (const float*)d_in[13];
  float* out = (float*)d_out;

  char* ws = (char*)d_ws;
  float* acc = (float*)ws;                               // [0]=recon ss, [1]=vq ss
  unsigned short* zeropg = (unsigned short*)(ws + 256);  // 512B zero page
  char* p = ws + 1024;
  unsigned short* wb2  = (unsigned short*)p; p += 524288;  // conv2 16*8*4*512*2
  unsigned short* wb3  = (unsigned short*)p; p += 147456;  // conv3  9*8*2*512*2
  unsigned short* wb4  = (unsigned short*)p; p += 36864;   // conv4 9*4*512*2
  unsigned short* wbd1 = (unsigned short*)p; p += 262144;  // dc1 4*4*4*4*512*2
  unsigned short* wbd2 = (unsigned short*)p; p += 524288;  // dc2 4*4*8*4*512*2
  unsigned short* cbf  = (unsigned short*)p; p += 65536;   // cb frags
  float*          cnrm = (float*)p;          p += 2048;
  float*          wc1  = (float*)p;          p += 24576;   // conv1 [tap][co] fp32
  size_t fixed = (size_t)(p - ws);

  // full-batch intermediates
  unsigned short* h1 = (unsigned short*)p; p += 67108864ull;  // h1 / d1 slot
  unsigned short* h2 = (unsigned short*)p; p += 16777216ull;
  float*          ze = (float*)p;          p += 16777216ull;
  unsigned short* zq = (unsigned short*)p; p += 8388608ull;
  unsigned short* d2 = (unsigned short*)p;
  size_t base = fixed + 67108864ull + 16777216ull + 16777216ull + 8388608ull;
  int CD = 64;
  while (CD > 1 && base + (size_t)CD * 4194304ull > ws_size) CD >>= 1;

  hipMemsetAsync(ws, 0, 1024, stream);   // loss accumulators + zero page
  repack_conv_w<128, 16, 4><<<(16 * 8 * 4 * 512 + 255) / 256, 256, 0, stream>>>(ew2, wb2, 128);
  repack_conv_w<128, 9, 2><<<(9 * 8 * 2 * 512 + 255) / 256, 256, 0, stream>>>(ew3, wb3, 64);
  repack_conv4_w<<<(9 * 4 * 512 + 255) / 256, 256, 0, stream>>>(dw3, wb4);
  repack_deconv_w<64, 128, 4><<<(16 * 4 * 4 * 512 + 255) / 256, 256, 0, stream>>>(dw1, wbd1);
  repack_deconv_w<128, 128, 4><<<(16 * 8 * 4 * 512 + 255) / 256, 256, 0, stream>>>(dw2, wbd2);
  repack_cb<<<128, 256, 0, stream>>>(cb, cbf);
  cnorm_k<<<2, 256, 0, stream>>>(cb, cnrm);
  repack_conv1_w<<<24, 256, 0, stream>>>(ew1, wc1);

  // ---- encoder, full batch ----
  conv1_k<<<1024, 256, 0, stream>>>(x, wc1, eb1, h1);
  // conv2: M=65536, block M=256 -> 256 blocks, NT=4 (full CO)
  mconv_k<128, 128, 4, 2, 64, 64, 32, 32, 16, 4, 2, 1, true, false>
      <<<256, 256, 0, stream>>>(h1, wb2, eb2, h2, zeropg);
  // conv3: M=65536 -> 256 blocks, NT=2 (CO=64)
  mconv_k<128, 64, 2, 2, 32, 32, 32, 32, 9, 3, 1, 1, false, true>
      <<<256, 256, 0, stream>>>(h2, wb3, eb3, ze, zeropg);
  vq2_k<<<512, 256, 0, stream>>>(ze, cb, cbf, cnrm, zq, acc + 1);
  // dc1: M=65536 -> 256 blocks, NT=4, 4 cls internal
  mconv_k<64, 128, 4, 2, 32, 32, 32, 32, 4, 2, 1, 4, true, false>
      <<<256, 256, 0, stream>>>(zq, wbd1, db1, h1, zeropg);

  // ---- decoder, chunked over d2 ----
  for (int n0 = 0; n0 < 64; n0 += CD) {
    const unsigned short* d1c = h1 + (size_t)n0 * 524288;   // 64*64*128
    // dc2: M=CD*4096 -> CD*16 blocks, NT=4, 4 cls internal
    mconv_k<128, 128, 4, 2, 64, 64, 64, 64, 4, 2, 1, 4, true, false>
        <<<CD * 16, 256, 0, stream>>>(d1c, wbd2, db2, d2, zeropg);
    conv4_k<<<CD * 32, 256, 0, stream>>>(d2, wb4, db3, x + (size_t)n0 * 49152,
                                         out + (size_t)n0 * 49152, acc, zeropg);
  }
  finalize_k<<<1, 64, 0, stream>>>(acc, out);
}

// Round 8
// 1149.614 us; speedup vs baseline: 1.1841x; 1.1841x over previous
//
#include <hip/hip_runtime.h>
#include <hip/hip_bf16.h>

// ---- VQ-VAE forward, round 8 ----------------------------------------------
// r7 post-mortem: parity-fused mconv (256-block grids) LOST -- latency-bound
// kernels need block count more than A-reuse; conv4 S=8 + full-batch d2
// (268MB > L3) hit 783MB FETCH. r8: revert mconv/conv4 to r6 forms (1103us)
// and force decoder chunk CD=16 so d2 chunk (64MB) stays L3-resident between
// dc2 (producer) and conv4 (consumer); d2 buffer re-dirtied in place each
// chunk -> d2 ~never round-trips HBM. Grids recomputed exactly.
// Layouts (HW-verified): 32x32x16_bf16 A[m=lane&31][k=(lane>>5)*8+j],
//   D: col=lane&31, row=(reg&3)+8*(reg>>2)+4*(lane>>5).
// 16x16x32_bf16 A[m=lane&15][k=(lane>>4)*8+j], D: col=lane&15,
//   row=(lane>>4)*4+reg.
// Deconv k4s2p1 parity (a,b): out(2q+a,2r+b) += in(q+a-i, r+b-j)*
//   w[ci][co][2i+1-a][2j+1-b]  (verified r2-r7).

typedef __attribute__((ext_vector_type(8))) short short8;
typedef __attribute__((ext_vector_type(16))) float f32x16;
typedef __attribute__((ext_vector_type(4))) float f32x4;

__device__ __forceinline__ unsigned short f2bf(float f) {
  union { __hip_bfloat16 b; unsigned short u; } cv;
  cv.b = __float2bfloat16(f);
  return cv.u;
}
__device__ __forceinline__ unsigned pack2bf(float a, float b) {
  return (unsigned)f2bf(a) | ((unsigned)f2bf(b) << 16);
}

// ---------------- weight repack: conv layers  w[CO][CI][NTAP] fp32 -> frags
// layout: [tap][kc][ntall][lane][8]
template<int CI, int NTAP, int NTALL>
__global__ void repack_conv_w(const float* __restrict__ w,
                              unsigned short* __restrict__ wb, int co_real) {
  const int KC = CI / 16;
  const int total = NTAP * KC * NTALL * 512;
  int i = blockIdx.x * 256 + threadIdx.x;
  if (i >= total) return;
  int j = i & 7, lane = (i >> 3) & 63, t2 = i >> 9;
  int nt = t2 % NTALL; t2 /= NTALL;
  int kc = t2 % KC; int tap = t2 / KC;
  int co = nt * 32 + (lane & 31);
  int ci = kc * 16 + (lane >> 5) * 8 + j;
  float v = (co < co_real) ? w[(co * CI + ci) * NTAP + tap] : 0.f;
  wb[i] = f2bf(v);
}

// ---------------- weight repack: deconv  w[CI][CO][4][4] fp32 -> frags/class
// layout: [cls][tap][kc][ntall][lane][8]
template<int CI, int CO, int NTALL>
__global__ void repack_deconv_w(const float* __restrict__ w,
                                unsigned short* __restrict__ wb) {
  const int KC = CI / 16;
  const int total = 16 * KC * NTALL * 512;
  int i = blockIdx.x * 256 + threadIdx.x;
  if (i >= total) return;
  int j = i & 7, lane = (i >> 3) & 63, t2 = i >> 9;
  int nt = t2 % NTALL; t2 /= NTALL;
  int kc = t2 % KC; t2 /= KC;
  int tap = t2 & 3, cls = t2 >> 2;
  int a = cls >> 1, b = cls & 1, ti = tap >> 1, tj = tap & 1;
  int kh = 2 * ti + 1 - a, kw = 2 * tj + 1 - b;
  int co = nt * 32 + (lane & 31);
  int ci = kc * 16 + (lane >> 5) * 8 + j;
  wb[i] = f2bf(w[((ci * CO + co) * 4 + kh) * 4 + kw]);
}

// ---------------- weight repack: conv4 16x16 frags  dw3[3][128][3][3]
__global__ void repack_conv4_w(const float* __restrict__ w,
                               unsigned short* __restrict__ wb) {
  const int total = 9 * 4 * 512;
  int i = blockIdx.x * 256 + threadIdx.x;
  if (i >= total) return;
  int j = i & 7, lane = (i >> 3) & 63, tk = i >> 9;
  int kc = tk & 3, t = tk >> 2;
  int co = lane & 15;
  int ci = kc * 32 + (lane >> 4) * 8 + j;
  float v = (co < 3) ? w[(co * 128 + ci) * 9 + t] : 0.f;
  wb[i] = f2bf(v);
}

// ---------------- weight repack: conv1  ew1[128][3][4][4] -> wc1[tap*128+co] fp32
__global__ void repack_conv1_w(const float* __restrict__ w,
                               float* __restrict__ wc1) {
  int i = blockIdx.x * 256 + threadIdx.x;   // 6144
  if (i >= 6144) return;
  int tap = i >> 7, co = i & 127;
  wc1[i] = w[co * 48 + tap];
}

// ---------------- codebook repack -> bf16 B-frags [tile16][kc4][lane64][8]
__global__ void repack_cb(const float* __restrict__ cb,
                          unsigned short* __restrict__ cbf) {
  int i = blockIdx.x * 256 + threadIdx.x;   // 32768
  int j = i & 7, lane = (i >> 3) & 63;
  int kc = (i >> 9) & 3, tile = i >> 11;
  int code = tile * 32 + (lane & 31);
  int d = kc * 16 + (lane >> 5) * 8 + j;
  cbf[i] = f2bf(cb[code * 64 + d]);
}
__global__ void cnorm_k(const float* __restrict__ cb, float* __restrict__ cn) {
  int k = blockIdx.x * 256 + threadIdx.x;
  if (k >= 512) return;
  const float4* r = (const float4*)(cb + k * 64);
  float s = 0.f;
  #pragma unroll
  for (int q = 0; q < 16; ++q) {
    float4 v = r[q];
    s = fmaf(v.x, v.x, s); s = fmaf(v.y, v.y, s);
    s = fmaf(v.z, v.z, s); s = fmaf(v.w, v.w, s);
  }
  cn[k] = s;
}

// ---------------- conv1 v2: x NCHW fp32 [64,3,128,128] -> h1 NHWC bf16
__global__ __launch_bounds__(256, 4) void conv1_k(
    const float* __restrict__ x, const float* __restrict__ wc1,
    const float* __restrict__ bias, unsigned short* __restrict__ out) {
  __shared__ float swc[6144];          // [tap][co] 24 KB
  __shared__ float sx[3 * 10 * 132];   // [ci][r][c] 15.8 KB
  int tid = threadIdx.x;
  int n = blockIdx.x >> 4, ohq = blockIdx.x & 15;
  #pragma unroll
  for (int q = 0; q < 6; ++q) {
    int i = (q * 256 + tid) * 4;
    *(float4*)&swc[i] = *(const float4*)&wc1[i];
  }
  int ihb = 8 * ohq - 1;
  for (int i = tid; i < 3960; i += 256) {
    int ci = i / 1320, rem = i - ci * 1320;
    int r = rem / 132, c = rem - r * 132;
    int ih = ihb + r, iw = c - 1;
    float v = 0.f;
    if ((unsigned)ih < 128u && (unsigned)iw < 128u)
      v = x[(n * 3 + ci) * 16384 + ih * 128 + iw];
    sx[i] = v;
  }
  __syncthreads();
  int ow = tid >> 2, cg = tid & 3;
  #pragma unroll
  for (int cob = 0; cob < 2; ++cob) {
    int co0 = cob * 64 + cg * 16;
    float4 acc[4][4];
    float4 bq[4];
    #pragma unroll
    for (int q = 0; q < 4; ++q) bq[q] = *(const float4*)&bias[co0 + q * 4];
    #pragma unroll
    for (int o = 0; o < 4; ++o)
      #pragma unroll
      for (int q = 0; q < 4; ++q) acc[o][q] = bq[q];
    for (int ci = 0; ci < 3; ++ci)
      for (int kh = 0; kh < 4; ++kh) {
        #pragma unroll
        for (int kw = 0; kw < 4; ++kw) {
          int tap = ci * 16 + kh * 4 + kw;
          const float* wp = &swc[tap * 128 + co0];
          float4 w0 = *(const float4*)(wp);
          float4 w1 = *(const float4*)(wp + 4);
          float4 w2 = *(const float4*)(wp + 8);
          float4 w3 = *(const float4*)(wp + 12);
          const float* xp = &sx[ci * 1320 + kh * 132 + 2 * ow + kw];
          #pragma unroll
          for (int o = 0; o < 4; ++o) {
            float xv = xp[o * 264];
            acc[o][0].x = fmaf(xv, w0.x, acc[o][0].x);
            acc[o][0].y = fmaf(xv, w0.y, acc[o][0].y);
            acc[o][0].z = fmaf(xv, w0.z, acc[o][0].z);
            acc[o][0].w = fmaf(xv, w0.w, acc[o][0].w);
            acc[o][1].x = fmaf(xv, w1.x, acc[o][1].x);
            acc[o][1].y = fmaf(xv, w1.y, acc[o][1].y);
            acc[o][1].z = fmaf(xv, w1.z, acc[o][1].z);
            acc[o][1].w = fmaf(xv, w1.w, acc[o][1].w);
            acc[o][2].x = fmaf(xv, w2.x, acc[o][2].x);
            acc[o][2].y = fmaf(xv, w2.y, acc[o][2].y);
            acc[o][2].z = fmaf(xv, w2.z, acc[o][2].z);
            acc[o][2].w = fmaf(xv, w2.w, acc[o][2].w);
            acc[o][3].x = fmaf(xv, w3.x, acc[o][3].x);
            acc[o][3].y = fmaf(xv, w3.y, acc[o][3].y);
            acc[o][3].z = fmaf(xv, w3.z, acc[o][3].z);
            acc[o][3].w = fmaf(xv, w3.w, acc[o][3].w);
          }
        }
      }
    #pragma unroll
    for (int o = 0; o < 4; ++o) {
      int oh = ohq * 4 + o;
      unsigned short* op = out + ((size_t)(n * 64 + oh) * 64 + ow) * 128 + co0;
      uint4 u0, u1;
      u0.x = pack2bf(fmaxf(acc[o][0].x, 0.f), fmaxf(acc[o][0].y, 0.f));
      u0.y = pack2bf(fmaxf(acc[o][0].z, 0.f), fmaxf(acc[o][0].w, 0.f));
      u0.z = pack2bf(fmaxf(acc[o][1].x, 0.f), fmaxf(acc[o][1].y, 0.f));
      u0.w = pack2bf(fmaxf(acc[o][1].z, 0.f), fmaxf(acc[o][1].w, 0.f));
      u1.x = pack2bf(fmaxf(acc[o][2].x, 0.f), fmaxf(acc[o][2].y, 0.f));
      u1.y = pack2bf(fmaxf(acc[o][2].z, 0.f), fmaxf(acc[o][2].w, 0.f));
      u1.z = pack2bf(fmaxf(acc[o][3].x, 0.f), fmaxf(acc[o][3].y, 0.f));
      u1.w = pack2bf(fmaxf(acc[o][3].z, 0.f), fmaxf(acc[o][3].w, 0.f));
      *(uint4*)(op) = u0;
      *(uint4*)(op + 8) = u1;
    }
  }
}

// ---------------- generic MFMA conv / parity-deconv (r6 form)
// M = 32*S per wave (block M = 128*S), N = 32*NT per wave (cog = blockIdx.z).
// B-frags double-buffered in LDS per tap, prefetched via registers.
template<int CI, int CO, int NTALL, int NT, int S, int IH, int IW, int OH, int OW,
         int NTAP, int KW, int STRIDE, bool DECONV, bool RELU, bool F32OUT>
__global__ __launch_bounds__(256, 2) void mconv_k(
    const unsigned short* __restrict__ in, const unsigned short* __restrict__ wb,
    const float* __restrict__ bias, void* __restrict__ outv,
    const unsigned short* __restrict__ zeropg) {
  const int KC = CI / 16;
  const int TSZ = KC * NT * 512;       // shorts per staged tap slice
  const int STG = KC * NT / 4;         // uint4 per thread per stage
  __shared__ unsigned short sB[2][TSZ];
  int tid = threadIdx.x, lane = tid & 63, wv = tid >> 6;
  int m0 = blockIdx.x * (128 * S) + wv * (32 * S);
  int cls = DECONV ? blockIdx.y : 0;
  int cog = blockIdx.z;
  int ca = cls >> 1, cb2 = cls & 1;
  int khalf = lane >> 5;
  int n_[S], oh_[S], ow_[S];
  #pragma unroll
  for (int s = 0; s < S; ++s) {
    int mm = m0 + s * 32 + (lane & 31);
    n_[s] = mm / (OH * OW);
    int rem = mm % (OH * OW);
    oh_[s] = rem / OW; ow_[s] = rem % OW;
  }
  f32x16 acc[S][NT];
  #pragma unroll
  for (int s = 0; s < S; ++s)
    #pragma unroll
    for (int t = 0; t < NT; ++t)
      #pragma unroll
      for (int e = 0; e < 16; ++e) acc[s][t][e] = 0.f;

  const unsigned short* wcls = wb + (size_t)cls * NTAP * KC * NTALL * 512;
  uint4 st[STG];
  // prologue: stage tap 0 into buf 0
  #pragma unroll
  for (int q = 0; q < STG; ++q) {
    int i = q * 256 + tid;
    int kc = i / (NT * 64), r = i - kc * (NT * 64);
    st[q] = *(const uint4*)(wcls + (size_t)(kc * NTALL + cog * NT) * 512 + r * 8);
  }
  #pragma unroll
  for (int q = 0; q < STG; ++q) {
    int i = q * 256 + tid;
    *(uint4*)&sB[0][i * 8] = st[q];
  }
  __syncthreads();

  for (int t = 0; t < NTAP; ++t) {
    int cur = t & 1;
    if (t + 1 < NTAP) {
      const unsigned short* wt = wcls + (size_t)(t + 1) * KC * NTALL * 512;
      #pragma unroll
      for (int q = 0; q < STG; ++q) {
        int i = q * 256 + tid;
        int kc = i / (NT * 64), r = i - kc * (NT * 64);
        st[q] = *(const uint4*)(wt + (size_t)(kc * NTALL + cog * NT) * 512 + r * 8);
      }
    }
    const unsigned short* ap[S];
    #pragma unroll
    for (int s = 0; s < S; ++s) {
      int ih, iw;
      if (DECONV) { ih = oh_[s] + ca - (t >> 1); iw = ow_[s] + cb2 - (t & 1); }
      else        { ih = STRIDE * oh_[s] - 1 + t / KW; iw = STRIDE * ow_[s] - 1 + t % KW; }
      bool valid = ((unsigned)ih < (unsigned)IH) && ((unsigned)iw < (unsigned)IW);
      ap[s] = valid ? (in + ((size_t)(n_[s] * IH + ih) * IW + iw) * CI + khalf * 8)
                    : (zeropg + khalf * 8);
    }
    #pragma unroll
    for (int kc = 0; kc < KC; ++kc) {
      short8 a[S];
      #pragma unroll
      for (int s = 0; s < S; ++s) a[s] = *(const short8*)(ap[s] + kc * 16);
      #pragma unroll
      for (int nt = 0; nt < NT; ++nt) {
        short8 b = *(const short8*)&sB[cur][(kc * NT + nt) * 512 + lane * 8];
        #pragma unroll
        for (int s = 0; s < S; ++s)
          acc[s][nt] = __builtin_amdgcn_mfma_f32_32x32x16_bf16(a[s], b, acc[s][nt], 0, 0, 0);
      }
    }
    if (t + 1 < NTAP) {
      #pragma unroll
      for (int q = 0; q < STG; ++q) {
        int i = q * 256 + tid;
        *(uint4*)&sB[cur ^ 1][i * 8] = st[q];
      }
    }
    __syncthreads();
  }

  int col = lane & 31;
  #pragma unroll
  for (int s = 0; s < S; ++s)
    #pragma unroll
    for (int nt = 0; nt < NT; ++nt) {
      int co = (cog * NT + nt) * 32 + col;
      float bv = bias[co];
      #pragma unroll
      for (int r = 0; r < 16; ++r) {
        int mrow = (r & 3) + 8 * (r >> 2) + 4 * khalf;
        int mp = m0 + s * 32 + mrow;
        int n2 = mp / (OH * OW), r2 = mp % (OH * OW);
        int oh2 = r2 / OW, ow2 = r2 % OW;
        float v = acc[s][nt][r] + bv;
        if (RELU) v = fmaxf(v, 0.f);
        size_t idx;
        if (DECONV)
          idx = ((size_t)(n2 * (2 * OH) + 2 * oh2 + ca) * (2 * OW) + 2 * ow2 + cb2) * CO + co;
        else
          idx = ((size_t)(n2 * OH + oh2) * OW + ow2) * CO + co;
        if (F32OUT) ((float*)outv)[idx] = v;
        else        ((unsigned short*)outv)[idx] = f2bf(v);
      }
    }
}

// ---------------- VQ via MFMA, codebook frags staged in LDS (2 phases x 32KB)
__global__ __launch_bounds__(256, 2) void vq2_k(
    const float* __restrict__ ze, const float* __restrict__ cb,
    const unsigned short* __restrict__ cbf, const float* __restrict__ cnorm,
    unsigned short* __restrict__ zq, float* __restrict__ acc_loss) {
  __shared__ unsigned short sC[16384];   // 8 tiles of B-frags (32 KB)
  __shared__ int s_idx[4][32];
  int tid = threadIdx.x, lane = tid & 63, wv = tid >> 6;
  int m0 = blockIdx.x * 128 + wv * 32;
  int col = lane & 31, khalf = lane >> 5;
  const float* zrow = ze + (size_t)(m0 + col) * 64 + khalf * 8;
  short8 af[4];
  #pragma unroll
  for (int kc = 0; kc < 4; ++kc) {
    float4 a = *(const float4*)(zrow + kc * 16);
    float4 b = *(const float4*)(zrow + kc * 16 + 4);
    short8 f;
    f[0] = (short)f2bf(a.x); f[1] = (short)f2bf(a.y);
    f[2] = (short)f2bf(a.z); f[3] = (short)f2bf(a.w);
    f[4] = (short)f2bf(b.x); f[5] = (short)f2bf(b.y);
    f[6] = (short)f2bf(b.z); f[7] = (short)f2bf(b.w);
    af[kc] = f;
  }
  float best[16]; int bidx[16];
  #pragma unroll
  for (int r = 0; r < 16; ++r) { best[r] = 3.4e38f; bidx[r] = 0; }
  for (int half = 0; half < 2; ++half) {
    #pragma unroll
    for (int q = 0; q < 8; ++q) {
      int i = q * 256 + tid;
      *(uint4*)&sC[i * 8] = *(const uint4*)(cbf + half * 16384 + i * 8);
    }
    __syncthreads();
    #pragma unroll
    for (int t8 = 0; t8 < 8; ++t8) {
      int tt = half * 8 + t8;
      f32x16 acc;
      #pragma unroll
      for (int e = 0; e < 16; ++e) acc[e] = 0.f;
      #pragma unroll
      for (int kc = 0; kc < 4; ++kc) {
        short8 bf_ = *(const short8*)&sC[(t8 * 4 + kc) * 512 + lane * 8];
        acc = __builtin_amdgcn_mfma_f32_32x32x16_bf16(af[kc], bf_, acc, 0, 0, 0);
      }
      float cn = cnorm[tt * 32 + col];
      int code = tt * 32 + col;
      #pragma unroll
      for (int r = 0; r < 16; ++r) {
        float d = fmaf(-2.f, acc[r], cn);
        if (d < best[r]) { best[r] = d; bidx[r] = code; }
      }
    }
    __syncthreads();
  }
  #pragma unroll
  for (int off = 1; off < 32; off <<= 1) {
    #pragma unroll
    for (int r = 0; r < 16; ++r) {
      float ob = __shfl_xor(best[r], off, 64);
      int   oi = __shfl_xor(bidx[r], off, 64);
      if (ob < best[r]) { best[r] = ob; bidx[r] = oi; }
    }
  }
  if (col == 0) {
    #pragma unroll
    for (int r = 0; r < 16; ++r)
      s_idx[wv][(r & 3) + 8 * (r >> 2) + 4 * khalf] = bidx[r];
  }
  __syncthreads();
  int row = lane >> 1, half2 = lane & 1;
  int m = m0 + row;
  int idx = s_idx[wv][row];
  const float4* crow = (const float4*)(cb + idx * 64 + half2 * 32);
  const float4* zp = (const float4*)(ze + (size_t)m * 64 + half2 * 32);
  uint2* zqp = (uint2*)(zq + (size_t)m * 64 + half2 * 32);
  float lsum = 0.f;
  #pragma unroll
  for (int q = 0; q < 8; ++q) {
    float4 c4 = crow[q];
    float4 z4 = zp[q];
    uint2 u; u.x = pack2bf(c4.x, c4.y); u.y = pack2bf(c4.z, c4.w);
    zqp[q] = u;
    float d;
    d = z4.x - c4.x; lsum = fmaf(d, d, lsum);
    d = z4.y - c4.y; lsum = fmaf(d, d, lsum);
    d = z4.z - c4.z; lsum = fmaf(d, d, lsum);
    d = z4.w - c4.w; lsum = fmaf(d, d, lsum);
  }
  #pragma unroll
  for (int off = 32; off > 0; off >>= 1) lsum += __shfl_down(lsum, off, 64);
  if (lane == 0) atomicAdd(acc_loss, lsum);
}

// ---------------- conv4: d2 NHWC bf16 -> x_recon NCHW fp32 (+recon loss)
// 16x16x32 MFMA, N=16 (co pad 3->16), M=64/wave (4 subtiles); B in LDS.
__global__ __launch_bounds__(256, 2) void conv4_k(
    const unsigned short* __restrict__ in, const unsigned short* __restrict__ wb,
    const float* __restrict__ bias, const float* __restrict__ x,
    float* __restrict__ out, float* __restrict__ acc_loss,
    const unsigned short* __restrict__ zeropg) {
  __shared__ unsigned short sW[18432];   // 9 taps x 4 kc x 512 (36 KB)
  int tid = threadIdx.x, lane = tid & 63, wv = tid >> 6;
  #pragma unroll
  for (int q = 0; q < 9; ++q) {
    int i = q * 256 + tid;
    *(uint4*)&sW[i * 8] = *(const uint4*)(wb + i * 8);
  }
  int m0 = blockIdx.x * 256 + wv * 64;
  int quad = lane >> 4, mloc = lane & 15;
  int n_[4], oh_[4], ow_[4];
  #pragma unroll
  for (int s = 0; s < 4; ++s) {
    int mm = m0 + s * 16 + mloc;
    n_[s] = mm >> 14;
    int rem = mm & 16383;
    oh_[s] = rem >> 7; ow_[s] = rem & 127;
  }
  f32x4 acc[4];
  #pragma unroll
  for (int s = 0; s < 4; ++s)
    #pragma unroll
    for (int e = 0; e < 4; ++e) acc[s][e] = 0.f;
  __syncthreads();
  #pragma unroll
  for (int t = 0; t < 9; ++t) {
    int dh = t / 3 - 1, dw = t % 3 - 1;
    const unsigned short* ap[4];
    #pragma unroll
    for (int s = 0; s < 4; ++s) {
      int ih = oh_[s] + dh, iw = ow_[s] + dw;
      bool valid = ((unsigned)ih < 128u) && ((unsigned)iw < 128u);
      ap[s] = valid ? (in + ((size_t)(n_[s] * 128 + ih) * 128 + iw) * 128 + quad * 8)
                    : (zeropg + quad * 8);
    }
    #pragma unroll
    for (int kc = 0; kc < 4; ++kc) {
      short8 bf_ = *(const short8*)&sW[(t * 4 + kc) * 512 + lane * 8];
      #pragma unroll
      for (int s = 0; s < 4; ++s) {
        short8 a = *(const short8*)(ap[s] + kc * 32);
        acc[s] = __builtin_amdgcn_mfma_f32_16x16x32_bf16(a, bf_, acc[s], 0, 0, 0);
      }
    }
  }
  int co = lane & 15;
  float bv = (co < 3) ? bias[co] : 0.f;
  float lsum = 0.f;
  #pragma unroll
  for (int s = 0; s < 4; ++s)
    #pragma unroll
    for (int r = 0; r < 4; ++r) {
      int m = m0 + s * 16 + quad * 4 + r;
      if (co < 3) {
        float v = acc[s][r] + bv;
        int n2 = m >> 14, r2 = m & 16383;
        int gi = (n2 * 3 + co) * 16384 + r2;
        out[gi] = v;
        float d = v - x[gi];
        lsum = fmaf(d, d, lsum);
      }
    }
  #pragma unroll
  for (int off = 32; off > 0; off >>= 1) lsum += __shfl_down(lsum, off, 64);
  if (lane == 0) atomicAdd(acc_loss, lsum);
}

// ---------------- finalize losses
__global__ void finalize_k(const float* __restrict__ accv, float* __restrict__ out) {
  if (threadIdx.x == 0 && blockIdx.x == 0) {
    float recon = accv[0] / 3145728.0f;
    float vq = 1.25f * accv[1] / 4194304.0f;
    out[3145728] = recon + vq;
    out[3145729] = recon;
    out[3145730] = vq;
  }
}

extern "C" void kernel_launch(void* const* d_in, const int* in_sizes, int n_in,
                              void* d_out, int out_size, void* d_ws, size_t ws_size,
                              hipStream_t stream) {
  const float* x   = (const float*)d_in[0];
  const float* ew1 = (const float*)d_in[1];
  const float* eb1 = (const float*)d_in[2];
  const float* ew2 = (const float*)d_in[3];
  const float* eb2 = (const float*)d_in[4];
  const float* ew3 = (const float*)d_in[5];
  const float* eb3 = (const float*)d_in[6];
  const float* cb  = (const float*)d_in[7];
  const float* dw1 = (const float*)d_in[8];
  const float* db1 = (const float*)d_in[9];
  const float* dw2 = (const float*)d_in[10];
  const float* db2 = (const float*)d_in[11];
  const float* dw3 = (const float*)d_in[12];
  const float* db3 = (const float*)d_in[13];
  float* out = (float*)d_out;

  char* ws = (char*)d_ws;
  float* acc = (float*)ws;                               // [0]=recon ss, [1]=vq ss
  unsigned short* zeropg = (unsigned short*)(ws + 256);  // 512B zero page
  char* p = ws + 1024;
  unsigned short* wb2  = (unsigned short*)p; p += 524288;  // conv2 16*8*4*512*2
  unsigned short* wb3  = (unsigned short*)p; p += 147456;  // conv3  9*8*2*512*2
  unsigned short* wb4  = (unsigned short*)p; p += 36864;   // conv4 9*4*512*2
  unsigned short* wbd1 = (unsigned short*)p; p += 262144;  // dc1 4*4*4*4*512*2
  unsigned short* wbd2 = (unsigned short*)p; p += 524288;  // dc2 4*4*8*4*512*2
  unsigned short* cbf  = (unsigned short*)p; p += 65536;   // cb frags
  float*          cnrm = (float*)p;          p += 2048;
  float*          wc1  = (float*)p;          p += 24576;   // conv1 [tap][co] fp32
  size_t fixed = (size_t)(p - ws);

  // full-batch intermediates
  unsigned short* h1 = (unsigned short*)p; p += 67108864ull;  // h1 / d1 slot
  unsigned short* h2 = (unsigned short*)p; p += 16777216ull;
  float*          ze = (float*)p;          p += 16777216ull;
  unsigned short* zq = (unsigned short*)p; p += 8388608ull;
  unsigned short* d2 = (unsigned short*)p;
  size_t base = fixed + 67108864ull + 16777216ull + 16777216ull + 8388608ull;
  // CD capped at 16: d2 chunk = 64 MB stays L3-resident between dc2 and conv4
  int CD = 16;
  while (CD > 1 && base + (size_t)CD * 4194304ull > ws_size) CD >>= 1;

  hipMemsetAsync(ws, 0, 1024, stream);   // loss accumulators + zero page
  repack_conv_w<128, 16, 4><<<(16 * 8 * 4 * 512 + 255) / 256, 256, 0, stream>>>(ew2, wb2, 128);
  repack_conv_w<128, 9, 2><<<(9 * 8 * 2 * 512 + 255) / 256, 256, 0, stream>>>(ew3, wb3, 64);
  repack_conv4_w<<<(9 * 4 * 512 + 255) / 256, 256, 0, stream>>>(dw3, wb4);
  repack_deconv_w<64, 128, 4><<<(16 * 4 * 4 * 512 + 255) / 256, 256, 0, stream>>>(dw1, wbd1);
  repack_deconv_w<128, 128, 4><<<(16 * 8 * 4 * 512 + 255) / 256, 256, 0, stream>>>(dw2, wbd2);
  repack_cb<<<128, 256, 0, stream>>>(cb, cbf);
  cnorm_k<<<2, 256, 0, stream>>>(cb, cnrm);
  repack_conv1_w<<<24, 256, 0, stream>>>(ew1, wc1);

  // ---- encoder, full batch ----
  conv1_k<<<1024, 256, 0, stream>>>(x, wc1, eb1, h1);
  // conv2: M=65536, block M=512 (S=4) -> 128 x, cog z=2
  mconv_k<128, 128, 4, 2, 4, 64, 64, 32, 32, 16, 4, 2, false, true, false>
      <<<dim3(128, 1, 2), 256, 0, stream>>>(h1, wb2, eb2, h2, zeropg);
  // conv3: M=65536, block M=256 (S=2) -> 256 x, NT=2 covers CO=64
  mconv_k<128, 64, 2, 2, 2, 32, 32, 32, 32, 9, 3, 1, false, false, true>
      <<<dim3(256, 1, 1), 256, 0, stream>>>(h2, wb3, eb3, ze, zeropg);
  vq2_k<<<512, 256, 0, stream>>>(ze, cb, cbf, cnrm, zq, acc + 1);
  // dc1: M=65536, block M=512 -> 128 x, 4 cls, cog z=2
  mconv_k<64, 128, 4, 2, 4, 32, 32, 32, 32, 4, 2, 1, true, true, false>
      <<<dim3(128, 4, 2), 256, 0, stream>>>(zq, wbd1, db1, h1, zeropg);

  // ---- decoder, chunked over d2 (CD=16 -> 64MB chunk, L3-resident) ----
  for (int n0 = 0; n0 < 64; n0 += CD) {
    const unsigned short* d1c = h1 + (size_t)n0 * 524288;   // 64*64*128
    // dc2 chunk: M=CD*4096, block M=512 -> CD*8 x, 4 cls, cog z=2
    mconv_k<128, 128, 4, 2, 4, 64, 64, 64, 64, 4, 2, 1, true, true, false>
        <<<dim3(CD * 8, 4, 2), 256, 0, stream>>>(d1c, wbd2, db2, d2, zeropg);
    // conv4 chunk: M=CD*16384, block M=256 -> CD*64 blocks
    conv4_k<<<CD * 64, 256, 0, stream>>>(d2, wb4, db3, x + (size_t)n0 * 49152,
                                         out + (size_t)n0 * 49152, acc, zeropg);
  }
  finalize_k<<<1, 64, 0, stream>>>(acc, out);
}

// Round 9
// 1106.193 us; speedup vs baseline: 1.2306x; 1.0393x over previous
//
#include <hip/hip_runtime.h>
#include <hip/hip_bf16.h>

// ---- VQ-VAE forward, round 9 ----------------------------------------------
// r8 post-mortem: L3 producer-consumer blocking (CD=16) failed -- conv4 chunk
// FETCH unchanged (248MB x4), grid shrank, conv4 aggregate 440us. Lessons:
// (r7) block count/occupancy dominates; (r8) L3 blocking not exploitable.
// r9: full-batch decoder again + occupancy lever: all mconv S=4 -> S=2
// (64 acc VGPRs), __launch_bounds__(256,4) => 16 waves/CU (was 8), grids 2x.
// conv4 full-batch, (256,4).
// Layouts (HW-verified): 32x32x16_bf16 A[m=lane&31][k=(lane>>5)*8+j],
//   D: col=lane&31, row=(reg&3)+8*(reg>>2)+4*(lane>>5).
// 16x16x32_bf16 A[m=lane&15][k=(lane>>4)*8+j], D: col=lane&15,
//   row=(lane>>4)*4+reg.
// Deconv k4s2p1 parity (a,b): out(2q+a,2r+b) += in(q+a-i, r+b-j)*
//   w[ci][co][2i+1-a][2j+1-b]  (verified r2-r8).

typedef __attribute__((ext_vector_type(8))) short short8;
typedef __attribute__((ext_vector_type(16))) float f32x16;
typedef __attribute__((ext_vector_type(4))) float f32x4;

__device__ __forceinline__ unsigned short f2bf(float f) {
  union { __hip_bfloat16 b; unsigned short u; } cv;
  cv.b = __float2bfloat16(f);
  return cv.u;
}
__device__ __forceinline__ unsigned pack2bf(float a, float b) {
  return (unsigned)f2bf(a) | ((unsigned)f2bf(b) << 16);
}

// ---------------- weight repack: conv layers  w[CO][CI][NTAP] fp32 -> frags
// layout: [tap][kc][ntall][lane][8]
template<int CI, int NTAP, int NTALL>
__global__ void repack_conv_w(const float* __restrict__ w,
                              unsigned short* __restrict__ wb, int co_real) {
  const int KC = CI / 16;
  const int total = NTAP * KC * NTALL * 512;
  int i = blockIdx.x * 256 + threadIdx.x;
  if (i >= total) return;
  int j = i & 7, lane = (i >> 3) & 63, t2 = i >> 9;
  int nt = t2 % NTALL; t2 /= NTALL;
  int kc = t2 % KC; int tap = t2 / KC;
  int co = nt * 32 + (lane & 31);
  int ci = kc * 16 + (lane >> 5) * 8 + j;
  float v = (co < co_real) ? w[(co * CI + ci) * NTAP + tap] : 0.f;
  wb[i] = f2bf(v);
}

// ---------------- weight repack: deconv  w[CI][CO][4][4] fp32 -> frags/class
// layout: [cls][tap][kc][ntall][lane][8]
template<int CI, int CO, int NTALL>
__global__ void repack_deconv_w(const float* __restrict__ w,
                                unsigned short* __restrict__ wb) {
  const int KC = CI / 16;
  const int total = 16 * KC * NTALL * 512;
  int i = blockIdx.x * 256 + threadIdx.x;
  if (i >= total) return;
  int j = i & 7, lane = (i >> 3) & 63, t2 = i >> 9;
  int nt = t2 % NTALL; t2 /= NTALL;
  int kc = t2 % KC; t2 /= KC;
  int tap = t2 & 3, cls = t2 >> 2;
  int a = cls >> 1, b = cls & 1, ti = tap >> 1, tj = tap & 1;
  int kh = 2 * ti + 1 - a, kw = 2 * tj + 1 - b;
  int co = nt * 32 + (lane & 31);
  int ci = kc * 16 + (lane >> 5) * 8 + j;
  wb[i] = f2bf(w[((ci * CO + co) * 4 + kh) * 4 + kw]);
}

// ---------------- weight repack: conv4 16x16 frags  dw3[3][128][3][3]
__global__ void repack_conv4_w(const float* __restrict__ w,
                               unsigned short* __restrict__ wb) {
  const int total = 9 * 4 * 512;
  int i = blockIdx.x * 256 + threadIdx.x;
  if (i >= total) return;
  int j = i & 7, lane = (i >> 3) & 63, tk = i >> 9;
  int kc = tk & 3, t = tk >> 2;
  int co = lane & 15;
  int ci = kc * 32 + (lane >> 4) * 8 + j;
  float v = (co < 3) ? w[(co * 128 + ci) * 9 + t] : 0.f;
  wb[i] = f2bf(v);
}

// ---------------- weight repack: conv1  ew1[128][3][4][4] -> wc1[tap*128+co] fp32
__global__ void repack_conv1_w(const float* __restrict__ w,
                               float* __restrict__ wc1) {
  int i = blockIdx.x * 256 + threadIdx.x;   // 6144
  if (i >= 6144) return;
  int tap = i >> 7, co = i & 127;
  wc1[i] = w[co * 48 + tap];
}

// ---------------- codebook repack -> bf16 B-frags [tile16][kc4][lane64][8]
__global__ void repack_cb(const float* __restrict__ cb,
                          unsigned short* __restrict__ cbf) {
  int i = blockIdx.x * 256 + threadIdx.x;   // 32768
  int j = i & 7, lane = (i >> 3) & 63;
  int kc = (i >> 9) & 3, tile = i >> 11;
  int code = tile * 32 + (lane & 31);
  int d = kc * 16 + (lane >> 5) * 8 + j;
  cbf[i] = f2bf(cb[code * 64 + d]);
}
__global__ void cnorm_k(const float* __restrict__ cb, float* __restrict__ cn) {
  int k = blockIdx.x * 256 + threadIdx.x;
  if (k >= 512) return;
  const float4* r = (const float4*)(cb + k * 64);
  float s = 0.f;
  #pragma unroll
  for (int q = 0; q < 16; ++q) {
    float4 v = r[q];
    s = fmaf(v.x, v.x, s); s = fmaf(v.y, v.y, s);
    s = fmaf(v.z, v.z, s); s = fmaf(v.w, v.w, s);
  }
  cn[k] = s;
}

// ---------------- conv1 v2: x NCHW fp32 [64,3,128,128] -> h1 NHWC bf16
__global__ __launch_bounds__(256, 4) void conv1_k(
    const float* __restrict__ x, const float* __restrict__ wc1,
    const float* __restrict__ bias, unsigned short* __restrict__ out) {
  __shared__ float swc[6144];          // [tap][co] 24 KB
  __shared__ float sx[3 * 10 * 132];   // [ci][r][c] 15.8 KB
  int tid = threadIdx.x;
  int n = blockIdx.x >> 4, ohq = blockIdx.x & 15;
  #pragma unroll
  for (int q = 0; q < 6; ++q) {
    int i = (q * 256 + tid) * 4;
    *(float4*)&swc[i] = *(const float4*)&wc1[i];
  }
  int ihb = 8 * ohq - 1;
  for (int i = tid; i < 3960; i += 256) {
    int ci = i / 1320, rem = i - ci * 1320;
    int r = rem / 132, c = rem - r * 132;
    int ih = ihb + r, iw = c - 1;
    float v = 0.f;
    if ((unsigned)ih < 128u && (unsigned)iw < 128u)
      v = x[(n * 3 + ci) * 16384 + ih * 128 + iw];
    sx[i] = v;
  }
  __syncthreads();
  int ow = tid >> 2, cg = tid & 3;
  #pragma unroll
  for (int cob = 0; cob < 2; ++cob) {
    int co0 = cob * 64 + cg * 16;
    float4 acc[4][4];
    float4 bq[4];
    #pragma unroll
    for (int q = 0; q < 4; ++q) bq[q] = *(const float4*)&bias[co0 + q * 4];
    #pragma unroll
    for (int o = 0; o < 4; ++o)
      #pragma unroll
      for (int q = 0; q < 4; ++q) acc[o][q] = bq[q];
    for (int ci = 0; ci < 3; ++ci)
      for (int kh = 0; kh < 4; ++kh) {
        #pragma unroll
        for (int kw = 0; kw < 4; ++kw) {
          int tap = ci * 16 + kh * 4 + kw;
          const float* wp = &swc[tap * 128 + co0];
          float4 w0 = *(const float4*)(wp);
          float4 w1 = *(const float4*)(wp + 4);
          float4 w2 = *(const float4*)(wp + 8);
          float4 w3 = *(const float4*)(wp + 12);
          const float* xp = &sx[ci * 1320 + kh * 132 + 2 * ow + kw];
          #pragma unroll
          for (int o = 0; o < 4; ++o) {
            float xv = xp[o * 264];
            acc[o][0].x = fmaf(xv, w0.x, acc[o][0].x);
            acc[o][0].y = fmaf(xv, w0.y, acc[o][0].y);
            acc[o][0].z = fmaf(xv, w0.z, acc[o][0].z);
            acc[o][0].w = fmaf(xv, w0.w, acc[o][0].w);
            acc[o][1].x = fmaf(xv, w1.x, acc[o][1].x);
            acc[o][1].y = fmaf(xv, w1.y, acc[o][1].y);
            acc[o][1].z = fmaf(xv, w1.z, acc[o][1].z);
            acc[o][1].w = fmaf(xv, w1.w, acc[o][1].w);
            acc[o][2].x = fmaf(xv, w2.x, acc[o][2].x);
            acc[o][2].y = fmaf(xv, w2.y, acc[o][2].y);
            acc[o][2].z = fmaf(xv, w2.z, acc[o][2].z);
            acc[o][2].w = fmaf(xv, w2.w, acc[o][2].w);
            acc[o][3].x = fmaf(xv, w3.x, acc[o][3].x);
            acc[o][3].y = fmaf(xv, w3.y, acc[o][3].y);
            acc[o][3].z = fmaf(xv, w3.z, acc[o][3].z);
            acc[o][3].w = fmaf(xv, w3.w, acc[o][3].w);
          }
        }
      }
    #pragma unroll
    for (int o = 0; o < 4; ++o) {
      int oh = ohq * 4 + o;
      unsigned short* op = out + ((size_t)(n * 64 + oh) * 64 + ow) * 128 + co0;
      uint4 u0, u1;
      u0.x = pack2bf(fmaxf(acc[o][0].x, 0.f), fmaxf(acc[o][0].y, 0.f));
      u0.y = pack2bf(fmaxf(acc[o][0].z, 0.f), fmaxf(acc[o][0].w, 0.f));
      u0.z = pack2bf(fmaxf(acc[o][1].x, 0.f), fmaxf(acc[o][1].y, 0.f));
      u0.w = pack2bf(fmaxf(acc[o][1].z, 0.f), fmaxf(acc[o][1].w, 0.f));
      u1.x = pack2bf(fmaxf(acc[o][2].x, 0.f), fmaxf(acc[o][2].y, 0.f));
      u1.y = pack2bf(fmaxf(acc[o][2].z, 0.f), fmaxf(acc[o][2].w, 0.f));
      u1.z = pack2bf(fmaxf(acc[o][3].x, 0.f), fmaxf(acc[o][3].y, 0.f));
      u1.w = pack2bf(fmaxf(acc[o][3].z, 0.f), fmaxf(acc[o][3].w, 0.f));
      *(uint4*)(op) = u0;
      *(uint4*)(op + 8) = u1;
    }
  }
}

// ---------------- generic MFMA conv / parity-deconv (S=2, 4 blocks/CU)
// M = 32*S per wave (block M = 128*S), N = 32*NT per wave (cog = blockIdx.z).
// B-frags double-buffered in LDS per tap, prefetched via registers.
template<int CI, int CO, int NTALL, int NT, int S, int IH, int IW, int OH, int OW,
         int NTAP, int KW, int STRIDE, bool DECONV, bool RELU, bool F32OUT>
__global__ __launch_bounds__(256, 4) void mconv_k(
    const unsigned short* __restrict__ in, const unsigned short* __restrict__ wb,
    const float* __restrict__ bias, void* __restrict__ outv,
    const unsigned short* __restrict__ zeropg) {
  const int KC = CI / 16;
  const int TSZ = KC * NT * 512;       // shorts per staged tap slice
  const int STG = KC * NT / 4;         // uint4 per thread per stage
  __shared__ unsigned short sB[2][TSZ];
  int tid = threadIdx.x, lane = tid & 63, wv = tid >> 6;
  int m0 = blockIdx.x * (128 * S) + wv * (32 * S);
  int cls = DECONV ? blockIdx.y : 0;
  int cog = blockIdx.z;
  int ca = cls >> 1, cb2 = cls & 1;
  int khalf = lane >> 5;
  int n_[S], oh_[S], ow_[S];
  #pragma unroll
  for (int s = 0; s < S; ++s) {
    int mm = m0 + s * 32 + (lane & 31);
    n_[s] = mm / (OH * OW);
    int rem = mm % (OH * OW);
    oh_[s] = rem / OW; ow_[s] = rem % OW;
  }
  f32x16 acc[S][NT];
  #pragma unroll
  for (int s = 0; s < S; ++s)
    #pragma unroll
    for (int t = 0; t < NT; ++t)
      #pragma unroll
      for (int e = 0; e < 16; ++e) acc[s][t][e] = 0.f;

  const unsigned short* wcls = wb + (size_t)cls * NTAP * KC * NTALL * 512;
  uint4 st[STG];
  // prologue: stage tap 0 into buf 0
  #pragma unroll
  for (int q = 0; q < STG; ++q) {
    int i = q * 256 + tid;
    int kc = i / (NT * 64), r = i - kc * (NT * 64);
    st[q] = *(const uint4*)(wcls + (size_t)(kc * NTALL + cog * NT) * 512 + r * 8);
  }
  #pragma unroll
  for (int q = 0; q < STG; ++q) {
    int i = q * 256 + tid;
    *(uint4*)&sB[0][i * 8] = st[q];
  }
  __syncthreads();

  for (int t = 0; t < NTAP; ++t) {
    int cur = t & 1;
    if (t + 1 < NTAP) {
      const unsigned short* wt = wcls + (size_t)(t + 1) * KC * NTALL * 512;
      #pragma unroll
      for (int q = 0; q < STG; ++q) {
        int i = q * 256 + tid;
        int kc = i / (NT * 64), r = i - kc * (NT * 64);
        st[q] = *(const uint4*)(wt + (size_t)(kc * NTALL + cog * NT) * 512 + r * 8);
      }
    }
    const unsigned short* ap[S];
    #pragma unroll
    for (int s = 0; s < S; ++s) {
      int ih, iw;
      if (DECONV) { ih = oh_[s] + ca - (t >> 1); iw = ow_[s] + cb2 - (t & 1); }
      else        { ih = STRIDE * oh_[s] - 1 + t / KW; iw = STRIDE * ow_[s] - 1 + t % KW; }
      bool valid = ((unsigned)ih < (unsigned)IH) && ((unsigned)iw < (unsigned)IW);
      ap[s] = valid ? (in + ((size_t)(n_[s] * IH + ih) * IW + iw) * CI + khalf * 8)
                    : (zeropg + khalf * 8);
    }
    #pragma unroll
    for (int kc = 0; kc < KC; ++kc) {
      short8 a[S];
      #pragma unroll
      for (int s = 0; s < S; ++s) a[s] = *(const short8*)(ap[s] + kc * 16);
      #pragma unroll
      for (int nt = 0; nt < NT; ++nt) {
        short8 b = *(const short8*)&sB[cur][(kc * NT + nt) * 512 + lane * 8];
        #pragma unroll
        for (int s = 0; s < S; ++s)
          acc[s][nt] = __builtin_amdgcn_mfma_f32_32x32x16_bf16(a[s], b, acc[s][nt], 0, 0, 0);
      }
    }
    if (t + 1 < NTAP) {
      #pragma unroll
      for (int q = 0; q < STG; ++q) {
        int i = q * 256 + tid;
        *(uint4*)&sB[cur ^ 1][i * 8] = st[q];
      }
    }
    __syncthreads();
  }

  int col = lane & 31;
  #pragma unroll
  for (int s = 0; s < S; ++s)
    #pragma unroll
    for (int nt = 0; nt < NT; ++nt) {
      int co = (cog * NT + nt) * 32 + col;
      float bv = bias[co];
      #pragma unroll
      for (int r = 0; r < 16; ++r) {
        int mrow = (r & 3) + 8 * (r >> 2) + 4 * khalf;
        int mp = m0 + s * 32 + mrow;
        int n2 = mp / (OH * OW), r2 = mp % (OH * OW);
        int oh2 = r2 / OW, ow2 = r2 % OW;
        float v = acc[s][nt][r] + bv;
        if (RELU) v = fmaxf(v, 0.f);
        size_t idx;
        if (DECONV)
          idx = ((size_t)(n2 * (2 * OH) + 2 * oh2 + ca) * (2 * OW) + 2 * ow2 + cb2) * CO + co;
        else
          idx = ((size_t)(n2 * OH + oh2) * OW + ow2) * CO + co;
        if (F32OUT) ((float*)outv)[idx] = v;
        else        ((unsigned short*)outv)[idx] = f2bf(v);
      }
    }
}

// ---------------- VQ via MFMA, codebook frags staged in LDS (2 phases x 32KB)
__global__ __launch_bounds__(256, 2) void vq2_k(
    const float* __restrict__ ze, const float* __restrict__ cb,
    const unsigned short* __restrict__ cbf, const float* __restrict__ cnorm,
    unsigned short* __restrict__ zq, float* __restrict__ acc_loss) {
  __shared__ unsigned short sC[16384];   // 8 tiles of B-frags (32 KB)
  __shared__ int s_idx[4][32];
  int tid = threadIdx.x, lane = tid & 63, wv = tid >> 6;
  int m0 = blockIdx.x * 128 + wv * 32;
  int col = lane & 31, khalf = lane >> 5;
  const float* zrow = ze + (size_t)(m0 + col) * 64 + khalf * 8;
  short8 af[4];
  #pragma unroll
  for (int kc = 0; kc < 4; ++kc) {
    float4 a = *(const float4*)(zrow + kc * 16);
    float4 b = *(const float4*)(zrow + kc * 16 + 4);
    short8 f;
    f[0] = (short)f2bf(a.x); f[1] = (short)f2bf(a.y);
    f[2] = (short)f2bf(a.z); f[3] = (short)f2bf(a.w);
    f[4] = (short)f2bf(b.x); f[5] = (short)f2bf(b.y);
    f[6] = (short)f2bf(b.z); f[7] = (short)f2bf(b.w);
    af[kc] = f;
  }
  float best[16]; int bidx[16];
  #pragma unroll
  for (int r = 0; r < 16; ++r) { best[r] = 3.4e38f; bidx[r] = 0; }
  for (int half = 0; half < 2; ++half) {
    #pragma unroll
    for (int q = 0; q < 8; ++q) {
      int i = q * 256 + tid;
      *(uint4*)&sC[i * 8] = *(const uint4*)(cbf + half * 16384 + i * 8);
    }
    __syncthreads();
    #pragma unroll
    for (int t8 = 0; t8 < 8; ++t8) {
      int tt = half * 8 + t8;
      f32x16 acc;
      #pragma unroll
      for (int e = 0; e < 16; ++e) acc[e] = 0.f;
      #pragma unroll
      for (int kc = 0; kc < 4; ++kc) {
        short8 bf_ = *(const short8*)&sC[(t8 * 4 + kc) * 512 + lane * 8];
        acc = __builtin_amdgcn_mfma_f32_32x32x16_bf16(af[kc], bf_, acc, 0, 0, 0);
      }
      float cn = cnorm[tt * 32 + col];
      int code = tt * 32 + col;
      #pragma unroll
      for (int r = 0; r < 16; ++r) {
        float d = fmaf(-2.f, acc[r], cn);
        if (d < best[r]) { best[r] = d; bidx[r] = code; }
      }
    }
    __syncthreads();
  }
  #pragma unroll
  for (int off = 1; off < 32; off <<= 1) {
    #pragma unroll
    for (int r = 0; r < 16; ++r) {
      float ob = __shfl_xor(best[r], off, 64);
      int   oi = __shfl_xor(bidx[r], off, 64);
      if (ob < best[r]) { best[r] = ob; bidx[r] = oi; }
    }
  }
  if (col == 0) {
    #pragma unroll
    for (int r = 0; r < 16; ++r)
      s_idx[wv][(r & 3) + 8 * (r >> 2) + 4 * khalf] = bidx[r];
  }
  __syncthreads();
  int row = lane >> 1, half2 = lane & 1;
  int m = m0 + row;
  int idx = s_idx[wv][row];
  const float4* crow = (const float4*)(cb + idx * 64 + half2 * 32);
  const float4* zp = (const float4*)(ze + (size_t)m * 64 + half2 * 32);
  uint2* zqp = (uint2*)(zq + (size_t)m * 64 + half2 * 32);
  float lsum = 0.f;
  #pragma unroll
  for (int q = 0; q < 8; ++q) {
    float4 c4 = crow[q];
    float4 z4 = zp[q];
    uint2 u; u.x = pack2bf(c4.x, c4.y); u.y = pack2bf(c4.z, c4.w);
    zqp[q] = u;
    float d;
    d = z4.x - c4.x; lsum = fmaf(d, d, lsum);
    d = z4.y - c4.y; lsum = fmaf(d, d, lsum);
    d = z4.z - c4.z; lsum = fmaf(d, d, lsum);
    d = z4.w - c4.w; lsum = fmaf(d, d, lsum);
  }
  #pragma unroll
  for (int off = 32; off > 0; off >>= 1) lsum += __shfl_down(lsum, off, 64);
  if (lane == 0) atomicAdd(acc_loss, lsum);
}

// ---------------- conv4: d2 NHWC bf16 -> x_recon NCHW fp32 (+recon loss)
// 16x16x32 MFMA, N=16 (co pad 3->16), M=64/wave (4 subtiles); B in LDS.
__global__ __launch_bounds__(256, 4) void conv4_k(
    const unsigned short* __restrict__ in, const unsigned short* __restrict__ wb,
    const float* __restrict__ bias, const float* __restrict__ x,
    float* __restrict__ out, float* __restrict__ acc_loss,
    const unsigned short* __restrict__ zeropg) {
  __shared__ unsigned short sW[18432];   // 9 taps x 4 kc x 512 (36 KB)
  int tid = threadIdx.x, lane = tid & 63, wv = tid >> 6;
  #pragma unroll
  for (int q = 0; q < 9; ++q) {
    int i = q * 256 + tid;
    *(uint4*)&sW[i * 8] = *(const uint4*)(wb + i * 8);
  }
  int m0 = blockIdx.x * 256 + wv * 64;
  int quad = lane >> 4, mloc = lane & 15;
  int n_[4], oh_[4], ow_[4];
  #pragma unroll
  for (int s = 0; s < 4; ++s) {
    int mm = m0 + s * 16 + mloc;
    n_[s] = mm >> 14;
    int rem = mm & 16383;
    oh_[s] = rem >> 7; ow_[s] = rem & 127;
  }
  f32x4 acc[4];
  #pragma unroll
  for (int s = 0; s < 4; ++s)
    #pragma unroll
    for (int e = 0; e < 4; ++e) acc[s][e] = 0.f;
  __syncthreads();
  #pragma unroll
  for (int t = 0; t < 9; ++t) {
    int dh = t / 3 - 1, dw = t % 3 - 1;
    const unsigned short* ap[4];
    #pragma unroll
    for (int s = 0; s < 4; ++s) {
      int ih = oh_[s] + dh, iw = ow_[s] + dw;
      bool valid = ((unsigned)ih < 128u) && ((unsigned)iw < 128u);
      ap[s] = valid ? (in + ((size_t)(n_[s] * 128 + ih) * 128 + iw) * 128 + quad * 8)
                    : (zeropg + quad * 8);
    }
    #pragma unroll
    for (int kc = 0; kc < 4; ++kc) {
      short8 bf_ = *(const short8*)&sW[(t * 4 + kc) * 512 + lane * 8];
      #pragma unroll
      for (int s = 0; s < 4; ++s) {
        short8 a = *(const short8*)(ap[s] + kc * 32);
        acc[s] = __builtin_amdgcn_mfma_f32_16x16x32_bf16(a, bf_, acc[s], 0, 0, 0);
      }
    }
  }
  int co = lane & 15;
  float bv = (co < 3) ? bias[co] : 0.f;
  float lsum = 0.f;
  #pragma unroll
  for (int s = 0; s < 4; ++s)
    #pragma unroll
    for (int r = 0; r < 4; ++r) {
      int m = m0 + s * 16 + quad * 4 + r;
      if (co < 3) {
        float v = acc[s][r] + bv;
        int n2 = m >> 14, r2 = m & 16383;
        int gi = (n2 * 3 + co) * 16384 + r2;
        out[gi] = v;
        float d = v - x[gi];
        lsum = fmaf(d, d, lsum);
      }
    }
  #pragma unroll
  for (int off = 32; off > 0; off >>= 1) lsum += __shfl_down(lsum, off, 64);
  if (lane == 0) atomicAdd(acc_loss, lsum);
}

// ---------------- finalize losses
__global__ void finalize_k(const float* __restrict__ accv, float* __restrict__ out) {
  if (threadIdx.x == 0 && blockIdx.x == 0) {
    float recon = accv[0] / 3145728.0f;
    float vq = 1.25f * accv[1] / 4194304.0f;
    out[3145728] = recon + vq;
    out[3145729] = recon;
    out[3145730] = vq;
  }
}

extern "C" void kernel_launch(void* const* d_in, const int* in_sizes, int n_in,
                              void* d_out, int out_size, void* d_ws, size_t ws_size,
                              hipStream_t stream) {
  const float* x   = (const float*)d_in[0];
  const float* ew1 = (const float*)d_in[1];
  const float* eb1 = (const float*)d_in[2];
  const float* ew2 = (const float*)d_in[3];
  const float* eb2 = (const float*)d_in[4];
  const float* ew3 = (const float*)d_in[5];
  const float* eb3 = (const float*)d_in[6];
  const float* cb  = (const float*)d_in[7];
  const float* dw1 = (const float*)d_in[8];
  const float* db1 = (const float*)d_in[9];
  const float* dw2 = (const float*)d_in[10];
  const float* db2 = (const float*)d_in[11];
  const float* dw3 = (const float*)d_in[12];
  const float* db3 = (const float*)d_in[13];
  float* out = (float*)d_out;

  char* ws = (char*)d_ws;
  float* acc = (float*)ws;                               // [0]=recon ss, [1]=vq ss
  unsigned short* zeropg = (unsigned short*)(ws + 256);  // 512B zero page
  char* p = ws + 1024;
  unsigned short* wb2  = (unsigned short*)p; p += 524288;  // conv2 16*8*4*512*2
  unsigned short* wb3  = (unsigned short*)p; p += 147456;  // conv3  9*8*2*512*2
  unsigned short* wb4  = (unsigned short*)p; p += 36864;   // conv4 9*4*512*2
  unsigned short* wbd1 = (unsigned short*)p; p += 262144;  // dc1 4*4*4*4*512*2
  unsigned short* wbd2 = (unsigned short*)p; p += 524288;  // dc2 4*4*8*4*512*2
  unsigned short* cbf  = (unsigned short*)p; p += 65536;   // cb frags
  float*          cnrm = (float*)p;          p += 2048;
  float*          wc1  = (float*)p;          p += 24576;   // conv1 [tap][co] fp32
  size_t fixed = (size_t)(p - ws);

  // full-batch intermediates
  unsigned short* h1 = (unsigned short*)p; p += 67108864ull;  // h1 / d1 slot
  unsigned short* h2 = (unsigned short*)p; p += 16777216ull;
  float*          ze = (float*)p;          p += 16777216ull;
  unsigned short* zq = (unsigned short*)p; p += 8388608ull;
  unsigned short* d2 = (unsigned short*)p;
  size_t base = fixed + 67108864ull + 16777216ull + 16777216ull + 8388608ull;
  int CD = 64;
  while (CD > 1 && base + (size_t)CD * 4194304ull > ws_size) CD >>= 1;

  hipMemsetAsync(ws, 0, 1024, stream);   // loss accumulators + zero page
  repack_conv_w<128, 16, 4><<<(16 * 8 * 4 * 512 + 255) / 256, 256, 0, stream>>>(ew2, wb2, 128);
  repack_conv_w<128, 9, 2><<<(9 * 8 * 2 * 512 + 255) / 256, 256, 0, stream>>>(ew3, wb3, 64);
  repack_conv4_w<<<(9 * 4 * 512 + 255) / 256, 256, 0, stream>>>(dw3, wb4);
  repack_deconv_w<64, 128, 4><<<(16 * 4 * 4 * 512 + 255) / 256, 256, 0, stream>>>(dw1, wbd1);
  repack_deconv_w<128, 128, 4><<<(16 * 8 * 4 * 512 + 255) / 256, 256, 0, stream>>>(dw2, wbd2);
  repack_cb<<<128, 256, 0, stream>>>(cb, cbf);
  cnorm_k<<<2, 256, 0, stream>>>(cb, cnrm);
  repack_conv1_w<<<24, 256, 0, stream>>>(ew1, wc1);

  // ---- encoder, full batch ----
  conv1_k<<<1024, 256, 0, stream>>>(x, wc1, eb1, h1);
  // conv2: M=65536, block M=256 (S=2) -> 256 x, cog z=2 (512 blocks)
  mconv_k<128, 128, 4, 2, 2, 64, 64, 32, 32, 16, 4, 2, false, true, false>
      <<<dim3(256, 1, 2), 256, 0, stream>>>(h1, wb2, eb2, h2, zeropg);
  // conv3: M=65536, block M=256 (S=2) -> 256 x, NT=2 covers CO=64
  mconv_k<128, 64, 2, 2, 2, 32, 32, 32, 32, 9, 3, 1, false, false, true>
      <<<dim3(256, 1, 1), 256, 0, stream>>>(h2, wb3, eb3, ze, zeropg);
  vq2_k<<<512, 256, 0, stream>>>(ze, cb, cbf, cnrm, zq, acc + 1);
  // dc1: M=65536, block M=256 -> 256 x, 4 cls, cog z=2 (2048 blocks)
  mconv_k<64, 128, 4, 2, 2, 32, 32, 32, 32, 4, 2, 1, true, true, false>
      <<<dim3(256, 4, 2), 256, 0, stream>>>(zq, wbd1, db1, h1, zeropg);

  // ---- decoder, full batch (chunk loop degenerates to 1 iter when ws allows) ----
  for (int n0 = 0; n0 < 64; n0 += CD) {
    const unsigned short* d1c = h1 + (size_t)n0 * 524288;   // 64*64*128
    // dc2: M=CD*4096, block M=256 -> CD*16 x, 4 cls, cog z=2 (CD=64: 8192 blocks)
    mconv_k<128, 128, 4, 2, 2, 64, 64, 64, 64, 4, 2, 1, true, true, false>
        <<<dim3(CD * 16, 4, 2), 256, 0, stream>>>(d1c, wbd2, db2, d2, zeropg);
    // conv4: M=CD*16384, block M=256 -> CD*64 blocks (CD=64: 4096)
    conv4_k<<<CD * 64, 256, 0, stream>>>(d2, wb4, db3, x + (size_t)n0 * 49152,
                                         out + (size_t)n0 * 49152, acc, zeropg);
  }
  finalize_k<<<1, 64, 0, stream>>>(acc, out);
}